// Round 10
// baseline (284.284 us; speedup 1.0000x reference)
//
#include <hip/hip_runtime.h>
#include <hip/hip_bf16.h>

// B=512, K=256, D_MODEL=256, D_INNER=512.
// Identity: Hilbert gather/scatter cancels (per-row model):
// out = slots + LN(SiLU(slots@W1+b1)@W2+b2)*gamma+beta. adj/centroids unused.
//
// R8 = full 1-pass bf16 + max TLP.
//  Evidence (R6): dropping W-lo left absmax bit-identical (0.03125) -> error is
//  dominated by non-GEMM sources; drop X-lo/H-lo too (pure bf16 GEMM).
//  Evidence (R7): VGPR_Count=64 proves compiler sinks "prefetch" loads to use
//  sites; ILP-pipelining at source is illusory here. Buy TLP instead:
//  LDS 40 KB (sXh+sHh only) -> 4 blocks/CU; launch_bounds(512,8) -> 64 VGPR
//  target -> 8 waves/SIMD (2x R7). Loads sit at use sites by design.

#define MROWS (512*256)
#define DM 256
#define DI 512

#define BAR_NODRAIN() do { \
    asm volatile("s_waitcnt lgkmcnt(0)" ::: "memory"); \
    __builtin_amdgcn_s_barrier(); \
} while (0)

typedef __attribute__((ext_vector_type(8))) short  short8;
typedef __attribute__((ext_vector_type(4))) float  f32x4;

static __device__ __forceinline__ unsigned short f2bf(float f) {
    union { float f; unsigned u; } c; c.f = f;
    unsigned r = c.u + 0x7FFFu + ((c.u >> 16) & 1u);   // RNE
    return (unsigned short)(r >> 16);
}
static __device__ __forceinline__ f32x4 MFMA(short8 a, short8 b, f32x4 c) {
    return __builtin_amdgcn_mfma_f32_16x16x32_bf16(a, b, c, 0, 0, 0);
}

// ---- prep: fragment-major HI-only bf16 weights (512 shorts = 1KB per frag).
// W1H frag f = tile16*8+kt (tile16 0..31, kt 0..7):
//   elem e=lane*8+j -> W1[k=kt*32+(lane>>4)*8+j][i=tile16*16+(lane&15)]
// W2H frag f = dtile*16+ks (dtile 0..15, ks 0..15):
//   elem e          -> W2[i=ks*32+(lane>>4)*8+j][d=dtile*16+(lane&15)]
__global__ void gml_prep(const float* __restrict__ W1, const float* __restrict__ W2,
                         unsigned short* __restrict__ W1H, unsigned short* __restrict__ W2H)
{
    int t = blockIdx.x * 256 + threadIdx.x;      // 0 .. 131071
    int f = t >> 9, e = t & 511;
    int lane = e >> 3, j = e & 7;
    int l15 = lane & 15, lq = lane >> 4;
    {
        int tile16 = f >> 3, kt = f & 7;
        int i = tile16 * 16 + l15;
        int k = kt * 32 + lq * 8 + j;
        W1H[(size_t)f * 512 + e] = f2bf(W1[k * DI + i]);
    }
    {
        int dtile = f >> 4, ks = f & 15;
        int d = dtile * 16 + l15;
        int i = ks * 32 + lq * 8 + j;
        W2H[(size_t)f * 512 + e] = f2bf(W2[i * DM + d]);
    }
}

__global__ __launch_bounds__(512, 8)
void gml_main(const float* __restrict__ X,
              const float* __restrict__ b1, const float* __restrict__ b2,
              const float* __restrict__ gamma, const float* __restrict__ beta,
              const unsigned short* __restrict__ W1H, const unsigned short* __restrict__ W2H,
              float* __restrict__ out)
{
    // X hi: [64 rows][256 k] bf16, row stride 512B, byte-swizzle ^((row&7)<<4)
    __shared__ short sXh[64 * 256];   // 32 KB
    // H hi: [64 rows][64 k] bf16, row stride 128B, same swizzle
    __shared__ short sHh[64 * 64];    // 8 KB   -> total 40 KB -> 4 blocks/CU
    // LN partials aliased into sXh (dead after last layer-1 + barrier)
    float* pS = (float*)sXh;          // [4 strips][64 rows]
    float* pQ = pS + 256;

    const int tid  = threadIdx.x;
    const int w    = tid >> 6;        // wave 0..7
    const int lane = tid & 63;
    const int l15  = lane & 15;
    const int lq   = lane >> 4;
    const int half = w >> 2;          // row half owned for compute
    const int cs   = w & 3;           // column strip
    const int rowbase = blockIdx.x * 64;

    // ---- X -> LDS (bf16 hi). Wave w loads k-slice [w*32, w*32+32) for all 64 rows.
    #pragma unroll
    for (int rt = 0; rt < 4; ++rt) {
        const int row = rt * 16 + l15;
        const float* xp = X + (size_t)(rowbase + row) * DM + w * 32 + lq * 8;
        f32x4 xa = *(const f32x4*)xp;
        f32x4 xb = *(const f32x4*)(xp + 4);
        short8 h8;
        #pragma unroll
        for (int j = 0; j < 8; ++j) {
            float v = (j < 4) ? xa[j] : xb[j - 4];
            h8[j] = (short)f2bf(v);
        }
        const int byt = (row * 512 + (w * 32 + lq * 8) * 2) ^ ((row & 7) << 4);
        *(short8*)((char*)sXh + byt) = h8;
    }

    f32x4 acc2[2][4];
    #pragma unroll
    for (int rt = 0; rt < 2; ++rt)
        #pragma unroll
        for (int ot = 0; ot < 4; ++ot)
            acc2[rt][ot] = (f32x4){0.f, 0.f, 0.f, 0.f};

    BAR_NODRAIN();

    #pragma unroll 1
    for (int c = 0; c < 8; ++c) {
        const size_t fb1 = (size_t)((c * 4 + cs) * 8);   // this chunk's W1 frag base

        // ---------- layer 1: wave computes H[half*32..+32][c*64 + cs*16 .. +16]
        f32x4 acc1[2] = {(f32x4){0.f,0.f,0.f,0.f}, (f32x4){0.f,0.f,0.f,0.f}};

        #pragma unroll
        for (int kt = 0; kt < 8; ++kt) {
            const short8 wfrag = *(const short8*)(W1H + (fb1 + kt) * 512 + lane * 8);
            short8 ah[2];
            #pragma unroll
            for (int rt = 0; rt < 2; ++rt) {
                const int row = half * 32 + rt * 16 + l15;
                const int byt = (row * 512 + (kt * 32 + lq * 8) * 2) ^ ((row & 7) << 4);
                ah[rt] = *(const short8*)((char*)sXh + byt);
            }
            #pragma unroll
            for (int rt = 0; rt < 2; ++rt)
                acc1[rt] = MFMA(ah[rt], wfrag, acc1[rt]);
        }

        // ---------- bias + SiLU -> H LDS (bf16)
        const float bias = b1[c * 64 + cs * 16 + l15];
        #pragma unroll
        for (int rt = 0; rt < 2; ++rt) {
            #pragma unroll
            for (int r = 0; r < 4; ++r) {
                const int row = half * 32 + rt * 16 + lq * 4 + r;
                float x = acc1[rt][r] + bias;
                float s = x / (1.f + __expf(-x));
                const int byt = (row * 128 + (cs * 16 + l15) * 2) ^ ((row & 7) << 4);
                *(short*)((char*)sHh + byt) = (short)f2bf(s);
            }
        }
        BAR_NODRAIN();

        // ---------- layer 2: acc2 += H @ W2h[c*64..+64][cs*64 .. +64]
        #pragma unroll
        for (int kt2 = 0; kt2 < 2; ++kt2) {
            short8 a2h[2];
            #pragma unroll
            for (int rt = 0; rt < 2; ++rt) {
                const int row = half * 32 + rt * 16 + l15;
                const int byt = (row * 128 + (kt2 * 32 + lq * 8) * 2) ^ ((row & 7) << 4);
                a2h[rt] = *(const short8*)((char*)sHh + byt);
            }
            #pragma unroll
            for (int ot = 0; ot < 4; ++ot) {
                const size_t f2 = (size_t)((cs * 4 + ot) * 16 + c * 2 + kt2);
                const short8 vfrag = *(const short8*)(W2H + f2 * 512 + lane * 8);
                #pragma unroll
                for (int rt = 0; rt < 2; ++rt)
                    acc2[rt][ot] = MFMA(a2h[rt], vfrag, acc2[rt][ot]);
            }
        }
        BAR_NODRAIN();
    }

    // ---------- epilogue: +b2, block-wide LN over 256 cols, *gamma+beta, +residual
    float b2v[4];
    #pragma unroll
    for (int ot = 0; ot < 4; ++ot) b2v[ot] = b2[cs * 64 + ot * 16 + l15];

    #pragma unroll
    for (int rt = 0; rt < 2; ++rt) {
        #pragma unroll
        for (int r = 0; r < 4; ++r) {
            float s = 0.f, q = 0.f;
            #pragma unroll
            for (int ot = 0; ot < 4; ++ot) {
                float v = acc2[rt][ot][r] + b2v[ot];
                acc2[rt][ot][r] = v;
                s += v; q += v * v;
            }
            #pragma unroll
            for (int m = 1; m < 16; m <<= 1) {
                s += __shfl_xor(s, m, 64);
                q += __shfl_xor(q, m, 64);
            }
            if (l15 == 0) {
                const int rowl = half * 32 + rt * 16 + lq * 4 + r;
                pS[cs * 64 + rowl] = s;
                pQ[cs * 64 + rowl] = q;
            }
        }
    }
    __syncthreads();

    const float inv = 1.f / 256.f;
    #pragma unroll
    for (int rt = 0; rt < 2; ++rt) {
        #pragma unroll
        for (int r = 0; r < 4; ++r) {
            const int rowl = half * 32 + rt * 16 + lq * 4 + r;
            const float s = pS[rowl] + pS[64 + rowl] + pS[128 + rowl] + pS[192 + rowl];
            const float q = pQ[rowl] + pQ[64 + rowl] + pQ[128 + rowl] + pQ[192 + rowl];
            const float mean = s * inv;
            const float rstd = rsqrtf(q * inv - mean * mean + 1e-5f);
            const size_t rb = (size_t)(rowbase + rowl) * DM;
            #pragma unroll
            for (int ot = 0; ot < 4; ++ot) {
                const int col = cs * 64 + ot * 16 + l15;
                out[rb + col] = (acc2[rt][ot][r] - mean) * rstd * gamma[col] + beta[col] + X[rb + col];
            }
        }
    }
}

// ---- slow-but-correct fp32 fallback (only if ws is unexpectedly tiny)
__global__ __launch_bounds__(256)
void gml_naive(const float* __restrict__ X, const float* __restrict__ W1,
               const float* __restrict__ b1, const float* __restrict__ W2,
               const float* __restrict__ b2, const float* __restrict__ gamma,
               const float* __restrict__ beta, float* __restrict__ out)
{
    __shared__ float sx[DM];
    __shared__ float sh[DI];
    __shared__ float red[8];
    const int row = blockIdx.x, t = threadIdx.x;
    const float* xr = X + (size_t)row * DM;
    sx[t] = xr[t];
    __syncthreads();
    #pragma unroll
    for (int rep = 0; rep < 2; ++rep) {
        int i = t + rep * 256;
        float a = 0.f;
        for (int k = 0; k < DM; ++k) a += sx[k] * W1[k * DI + i];
        a += b1[i];
        sh[i] = a / (1.f + __expf(-a));
    }
    __syncthreads();
    float y = 0.f;
    for (int i = 0; i < DI; ++i) y += sh[i] * W2[i * DM + t];
    y += b2[t];
    float s = y, q = y * y;
    for (int m = 1; m < 64; m <<= 1) { s += __shfl_xor(s, m, 64); q += __shfl_xor(q, m, 64); }
    if ((t & 63) == 0) { red[t >> 6] = s; red[4 + (t >> 6)] = q; }
    __syncthreads();
    const float sum = red[0] + red[1] + red[2] + red[3];
    const float ssq = red[4] + red[5] + red[6] + red[7];
    const float mean = sum / 256.f;
    const float rstd = rsqrtf(ssq / 256.f - mean * mean + 1e-5f);
    out[(size_t)row * DM + t] = (y - mean) * rstd * gamma[t] + beta[t] + xr[t];
}

extern "C" void kernel_launch(void* const* d_in, const int* in_sizes, int n_in,
                              void* d_out, int out_size, void* d_ws, size_t ws_size,
                              hipStream_t stream)
{
    const float* slots = (const float*)d_in[0];
    // d_in[1]=adj, d_in[2]=centroids : unused (permutation cancels)
    const float* W1    = (const float*)d_in[3];
    const float* b1    = (const float*)d_in[4];
    const float* W2    = (const float*)d_in[5];
    const float* b2    = (const float*)d_in[6];
    const float* gamma = (const float*)d_in[7];
    const float* beta  = (const float*)d_in[8];
    float* out = (float*)d_out;

    const size_t need = (size_t)2 * 256 * 512 * sizeof(unsigned short);  // 512 KiB
    if (ws_size >= need) {
        unsigned short* W1H = (unsigned short*)d_ws;
        unsigned short* W2H = W1H + (size_t)256 * 512;
        hipLaunchKernelGGL(gml_prep, dim3(512), dim3(256), 0, stream, W1, W2, W1H, W2H);
        hipLaunchKernelGGL(gml_main, dim3(MROWS / 64), dim3(512), 0, stream,
                           slots, b1, b2, gamma, beta, W1H, W2H, out);
    } else {
        hipLaunchKernelGGL(gml_naive, dim3(MROWS), dim3(256), 0, stream,
                           slots, W1, b1, W2, b2, gamma, beta, out);
    }
}

// Round 11
// 217.727 us; speedup vs baseline: 1.3057x; 1.3057x over previous
//
#include <hip/hip_runtime.h>
#include <hip/hip_bf16.h>

// B=512, K=256, D_MODEL=256, D_INNER=512.
// Identity: Hilbert gather/scatter cancels (per-row model):
// out = slots + LN(SiLU(slots@W1+b1)@W2+b2)*gamma+beta. adj/centroids unused.
//
// R9 = R8 body (1-pass bf16; validated: R8 absmax 0.03125) with the register
// cliff fixed: launch_bounds(512,4). R8's (512,8) forced VGPR=32 < acc2's 32
// -> accumulator spills -> FETCH 176->581MB, MfmaUtil 9%. (512,4) allows 128;
// expect ~56-64 actual -> no spills, occupancy still 6-8 waves/SIMD via
// 40KB LDS (4 blocks/CU potential).

#define MROWS (512*256)
#define DM 256
#define DI 512

#define BAR_NODRAIN() do { \
    asm volatile("s_waitcnt lgkmcnt(0)" ::: "memory"); \
    __builtin_amdgcn_s_barrier(); \
} while (0)

typedef __attribute__((ext_vector_type(8))) short  short8;
typedef __attribute__((ext_vector_type(4))) float  f32x4;

static __device__ __forceinline__ unsigned short f2bf(float f) {
    union { float f; unsigned u; } c; c.f = f;
    unsigned r = c.u + 0x7FFFu + ((c.u >> 16) & 1u);   // RNE
    return (unsigned short)(r >> 16);
}
static __device__ __forceinline__ f32x4 MFMA(short8 a, short8 b, f32x4 c) {
    return __builtin_amdgcn_mfma_f32_16x16x32_bf16(a, b, c, 0, 0, 0);
}

// ---- prep: fragment-major HI-only bf16 weights (512 shorts = 1KB per frag).
// W1H frag f = tile16*8+kt (tile16 0..31, kt 0..7):
//   elem e=lane*8+j -> W1[k=kt*32+(lane>>4)*8+j][i=tile16*16+(lane&15)]
// W2H frag f = dtile*16+ks (dtile 0..15, ks 0..15):
//   elem e          -> W2[i=ks*32+(lane>>4)*8+j][d=dtile*16+(lane&15)]
__global__ void gml_prep(const float* __restrict__ W1, const float* __restrict__ W2,
                         unsigned short* __restrict__ W1H, unsigned short* __restrict__ W2H)
{
    int t = blockIdx.x * 256 + threadIdx.x;      // 0 .. 131071
    int f = t >> 9, e = t & 511;
    int lane = e >> 3, j = e & 7;
    int l15 = lane & 15, lq = lane >> 4;
    {
        int tile16 = f >> 3, kt = f & 7;
        int i = tile16 * 16 + l15;
        int k = kt * 32 + lq * 8 + j;
        W1H[(size_t)f * 512 + e] = f2bf(W1[k * DI + i]);
    }
    {
        int dtile = f >> 4, ks = f & 15;
        int d = dtile * 16 + l15;
        int i = ks * 32 + lq * 8 + j;
        W2H[(size_t)f * 512 + e] = f2bf(W2[i * DM + d]);
    }
}

__global__ __launch_bounds__(512, 4)
void gml_main(const float* __restrict__ X,
              const float* __restrict__ b1, const float* __restrict__ b2,
              const float* __restrict__ gamma, const float* __restrict__ beta,
              const unsigned short* __restrict__ W1H, const unsigned short* __restrict__ W2H,
              float* __restrict__ out)
{
    // X hi: [64 rows][256 k] bf16, row stride 512B, byte-swizzle ^((row&7)<<4)
    __shared__ short sXh[64 * 256];   // 32 KB
    // H hi: [64 rows][64 k] bf16, row stride 128B, same swizzle
    __shared__ short sHh[64 * 64];    // 8 KB   -> total 40 KB -> 4 blocks/CU
    // LN partials aliased into sXh (dead after last layer-1 + barrier)
    float* pS = (float*)sXh;          // [4 strips][64 rows]
    float* pQ = pS + 256;

    const int tid  = threadIdx.x;
    const int w    = tid >> 6;        // wave 0..7
    const int lane = tid & 63;
    const int l15  = lane & 15;
    const int lq   = lane >> 4;
    const int half = w >> 2;          // row half owned for compute
    const int cs   = w & 3;           // column strip
    const int rowbase = blockIdx.x * 64;

    // ---- X -> LDS (bf16 hi). Wave w loads k-slice [w*32, w*32+32) for all 64 rows.
    #pragma unroll
    for (int rt = 0; rt < 4; ++rt) {
        const int row = rt * 16 + l15;
        const float* xp = X + (size_t)(rowbase + row) * DM + w * 32 + lq * 8;
        f32x4 xa = *(const f32x4*)xp;
        f32x4 xb = *(const f32x4*)(xp + 4);
        short8 h8;
        #pragma unroll
        for (int j = 0; j < 8; ++j) {
            float v = (j < 4) ? xa[j] : xb[j - 4];
            h8[j] = (short)f2bf(v);
        }
        const int byt = (row * 512 + (w * 32 + lq * 8) * 2) ^ ((row & 7) << 4);
        *(short8*)((char*)sXh + byt) = h8;
    }

    f32x4 acc2[2][4];
    #pragma unroll
    for (int rt = 0; rt < 2; ++rt)
        #pragma unroll
        for (int ot = 0; ot < 4; ++ot)
            acc2[rt][ot] = (f32x4){0.f, 0.f, 0.f, 0.f};

    BAR_NODRAIN();

    #pragma unroll 1
    for (int c = 0; c < 8; ++c) {
        const size_t fb1 = (size_t)((c * 4 + cs) * 8);   // this chunk's W1 frag base

        // ---------- layer 1: wave computes H[half*32..+32][c*64 + cs*16 .. +16]
        f32x4 acc1[2] = {(f32x4){0.f,0.f,0.f,0.f}, (f32x4){0.f,0.f,0.f,0.f}};

        #pragma unroll
        for (int kt = 0; kt < 8; ++kt) {
            const short8 wfrag = *(const short8*)(W1H + (fb1 + kt) * 512 + lane * 8);
            short8 ah[2];
            #pragma unroll
            for (int rt = 0; rt < 2; ++rt) {
                const int row = half * 32 + rt * 16 + l15;
                const int byt = (row * 512 + (kt * 32 + lq * 8) * 2) ^ ((row & 7) << 4);
                ah[rt] = *(const short8*)((char*)sXh + byt);
            }
            #pragma unroll
            for (int rt = 0; rt < 2; ++rt)
                acc1[rt] = MFMA(ah[rt], wfrag, acc1[rt]);
        }

        // ---------- bias + SiLU -> H LDS (bf16)
        const float bias = b1[c * 64 + cs * 16 + l15];
        #pragma unroll
        for (int rt = 0; rt < 2; ++rt) {
            #pragma unroll
            for (int r = 0; r < 4; ++r) {
                const int row = half * 32 + rt * 16 + lq * 4 + r;
                float x = acc1[rt][r] + bias;
                float s = x / (1.f + __expf(-x));
                const int byt = (row * 128 + (cs * 16 + l15) * 2) ^ ((row & 7) << 4);
                *(short*)((char*)sHh + byt) = (short)f2bf(s);
            }
        }
        BAR_NODRAIN();

        // ---------- layer 2: acc2 += H @ W2h[c*64..+64][cs*64 .. +64]
        #pragma unroll
        for (int kt2 = 0; kt2 < 2; ++kt2) {
            short8 a2h[2];
            #pragma unroll
            for (int rt = 0; rt < 2; ++rt) {
                const int row = half * 32 + rt * 16 + l15;
                const int byt = (row * 128 + (kt2 * 32 + lq * 8) * 2) ^ ((row & 7) << 4);
                a2h[rt] = *(const short8*)((char*)sHh + byt);
            }
            #pragma unroll
            for (int ot = 0; ot < 4; ++ot) {
                const size_t f2 = (size_t)((cs * 4 + ot) * 16 + c * 2 + kt2);
                const short8 vfrag = *(const short8*)(W2H + f2 * 512 + lane * 8);
                #pragma unroll
                for (int rt = 0; rt < 2; ++rt)
                    acc2[rt][ot] = MFMA(a2h[rt], vfrag, acc2[rt][ot]);
            }
        }
        BAR_NODRAIN();
    }

    // ---------- epilogue: +b2, block-wide LN over 256 cols, *gamma+beta, +residual
    float b2v[4];
    #pragma unroll
    for (int ot = 0; ot < 4; ++ot) b2v[ot] = b2[cs * 64 + ot * 16 + l15];

    #pragma unroll
    for (int rt = 0; rt < 2; ++rt) {
        #pragma unroll
        for (int r = 0; r < 4; ++r) {
            float s = 0.f, q = 0.f;
            #pragma unroll
            for (int ot = 0; ot < 4; ++ot) {
                float v = acc2[rt][ot][r] + b2v[ot];
                acc2[rt][ot][r] = v;
                s += v; q += v * v;
            }
            #pragma unroll
            for (int m = 1; m < 16; m <<= 1) {
                s += __shfl_xor(s, m, 64);
                q += __shfl_xor(q, m, 64);
            }
            if (l15 == 0) {
                const int rowl = half * 32 + rt * 16 + lq * 4 + r;
                pS[cs * 64 + rowl] = s;
                pQ[cs * 64 + rowl] = q;
            }
        }
    }
    __syncthreads();

    const float inv = 1.f / 256.f;
    #pragma unroll
    for (int rt = 0; rt < 2; ++rt) {
        #pragma unroll
        for (int r = 0; r < 4; ++r) {
            const int rowl = half * 32 + rt * 16 + lq * 4 + r;
            const float s = pS[rowl] + pS[64 + rowl] + pS[128 + rowl] + pS[192 + rowl];
            const float q = pQ[rowl] + pQ[64 + rowl] + pQ[128 + rowl] + pQ[192 + rowl];
            const float mean = s * inv;
            const float rstd = rsqrtf(q * inv - mean * mean + 1e-5f);
            const size_t rb = (size_t)(rowbase + rowl) * DM;
            #pragma unroll
            for (int ot = 0; ot < 4; ++ot) {
                const int col = cs * 64 + ot * 16 + l15;
                out[rb + col] = (acc2[rt][ot][r] - mean) * rstd * gamma[col] + beta[col] + X[rb + col];
            }
        }
    }
}

// ---- slow-but-correct fp32 fallback (only if ws is unexpectedly tiny)
__global__ __launch_bounds__(256)
void gml_naive(const float* __restrict__ X, const float* __restrict__ W1,
               const float* __restrict__ b1, const float* __restrict__ W2,
               const float* __restrict__ b2, const float* __restrict__ gamma,
               const float* __restrict__ beta, float* __restrict__ out)
{
    __shared__ float sx[DM];
    __shared__ float sh[DI];
    __shared__ float red[8];
    const int row = blockIdx.x, t = threadIdx.x;
    const float* xr = X + (size_t)row * DM;
    sx[t] = xr[t];
    __syncthreads();
    #pragma unroll
    for (int rep = 0; rep < 2; ++rep) {
        int i = t + rep * 256;
        float a = 0.f;
        for (int k = 0; k < DM; ++k) a += sx[k] * W1[k * DI + i];
        a += b1[i];
        sh[i] = a / (1.f + __expf(-a));
    }
    __syncthreads();
    float y = 0.f;
    for (int i = 0; i < DI; ++i) y += sh[i] * W2[i * DM + t];
    y += b2[t];
    float s = y, q = y * y;
    for (int m = 1; m < 64; m <<= 1) { s += __shfl_xor(s, m, 64); q += __shfl_xor(q, m, 64); }
    if ((t & 63) == 0) { red[t >> 6] = s; red[4 + (t >> 6)] = q; }
    __syncthreads();
    const float sum = red[0] + red[1] + red[2] + red[3];
    const float ssq = red[4] + red[5] + red[6] + red[7];
    const float mean = sum / 256.f;
    const float rstd = rsqrtf(ssq / 256.f - mean * mean + 1e-5f);
    out[(size_t)row * DM + t] = (y - mean) * rstd * gamma[t] + beta[t] + xr[t];
}

extern "C" void kernel_launch(void* const* d_in, const int* in_sizes, int n_in,
                              void* d_out, int out_size, void* d_ws, size_t ws_size,
                              hipStream_t stream)
{
    const float* slots = (const float*)d_in[0];
    // d_in[1]=adj, d_in[2]=centroids : unused (permutation cancels)
    const float* W1    = (const float*)d_in[3];
    const float* b1    = (const float*)d_in[4];
    const float* W2    = (const float*)d_in[5];
    const float* b2    = (const float*)d_in[6];
    const float* gamma = (const float*)d_in[7];
    const float* beta  = (const float*)d_in[8];
    float* out = (float*)d_out;

    const size_t need = (size_t)2 * 256 * 512 * sizeof(unsigned short);  // 512 KiB
    if (ws_size >= need) {
        unsigned short* W1H = (unsigned short*)d_ws;
        unsigned short* W2H = W1H + (size_t)256 * 512;
        hipLaunchKernelGGL(gml_prep, dim3(512), dim3(256), 0, stream, W1, W2, W1H, W2H);
        hipLaunchKernelGGL(gml_main, dim3(MROWS / 64), dim3(512), 0, stream,
                           slots, b1, b2, gamma, beta, W1H, W2H, out);
    } else {
        hipLaunchKernelGGL(gml_naive, dim3(MROWS), dim3(256), 0, stream,
                           slots, W1, b1, W2, b2, gamma, beta, out);
    }
}